// Round 8
// baseline (388.784 us; speedup 1.0000x reference)
//
#include <hip/hip_runtime.h>

#define B_ 64
#define H_ 32
#define DN 512
#define DR 64
#define BS 128
#define TK 32
#define MAXKV 4096
#define ROWF 584              // 576 data + 8 pad f16 = 1168 B
#define LOG2E 1.44269504088896340736f
#define SCALE_ (1.0f/24.0f)   // 1/sqrt(576)
#define NEG_INF -1e30f

typedef float    f32x4 __attribute__((ext_vector_type(4)));
typedef _Float16 f16x4 __attribute__((ext_vector_type(4)));
typedef _Float16 f16x2 __attribute__((ext_vector_type(2)));

#define MFMA16 __builtin_amdgcn_mfma_f32_16x16x16f16

__device__ __forceinline__ f16x4 cvt4(f32x4 a) {
  f16x2 lo = __builtin_bit_cast(f16x2, __builtin_amdgcn_cvt_pkrtz(a[0], a[1]));
  f16x2 hi = __builtin_bit_cast(f16x2, __builtin_amdgcn_cvt_pkrtz(a[2], a[3]));
  f16x4 r; r[0] = lo[0]; r[1] = lo[1]; r[2] = hi[0]; r[3] = hi[1];
  return r;
}

// LDS-only barrier: drains lgkm, leaves global loads (vmcnt) in flight.
__device__ __forceinline__ void ldsbar() {
  asm volatile("s_waitcnt lgkmcnt(0)" ::: "memory");
  __builtin_amdgcn_sched_barrier(0);
  __builtin_amdgcn_s_barrier();
  __builtin_amdgcn_sched_barrier(0);
}

// Kernel 1: per (b, chunk) flash-decode partial. TK=32 tiles, 4 waves,
// f16 K-tile double-buffered in LDS (78.3 KB total -> 2 blocks/CU).
// Staging is reg-staged async: tile t+2's global loads are issued in the
// PV window of tile t and consumed (cvt+ds_write) in the PV window of
// tile t+1 -- lgkm-only barriers keep them in flight across all phases.
__global__ __launch_bounds__(256, 2) void mla_chunk(
    const float* __restrict__ qn, const float* __restrict__ qr,
    const float* __restrict__ kvn, const float* __restrict__ kvr,
    const int* __restrict__ btab, const int* __restrict__ kseq,
    _Float16* __restrict__ po, float* __restrict__ ml,
    const int nc, const int chunk)
{
  // XCD swizzle (grid divisible by 8): consecutive bc share an XCD.
  const int raw = blockIdx.x;
  const int bc  = (raw & 7) * ((int)gridDim.x >> 3) + (raw >> 3);
  const int b = bc / nc, c = bc - b * nc;
  const int klen = kseq[b];
  const int kbase = c * chunk;
  if (kbase >= klen) return;
  const int nvalid = min(chunk, klen - kbase);
  const int nsb = (nvalid + TK - 1) / TK;

  const int tid = threadIdx.x;
  const int w = tid >> 6, l = tid & 63, l15 = l & 15, lg = l >> 4;
  const int kd = lg * 4;
  const int wk = w >> 1, wh = w & 1;     // QK roles: key-half, head-half
  const int hw = w >> 1, dv = w & 1;     // PV roles: head-half, dim-half

  __shared__ _Float16 KT[2][TK][ROWF];   // 74,752 B, swizzled 8B slots
  __shared__ _Float16 Plds[H_][40];      // 2,560 B
  __shared__ float m_tab[2][H_], l_tab[2][H_];
  __shared__ float Mrun[2][H_], Lrun[2][H_];

  if (tid < H_) { Mrun[0][tid] = NEG_INF; Lrun[0][tid] = 0.f; }

  f32x4 acc[16];
  #pragma unroll
  for (int i = 0; i < 16; ++i) acc[i] = (f32x4){0.f, 0.f, 0.f, 0.f};

  // ---- Q fragments (nope 0..31 + rope 32..35) in f16 regs ----
  // B-frag: col = l15 -> head wh*16+l15, k = kd+i.
  f16x4 Qn[36];
  {
    const float* q_ = qn + ((size_t)b * H_ + wh * 16 + l15) * DN + kd;
    #pragma unroll
    for (int i = 0; i < 32; ++i) Qn[i] = cvt4(*(const f32x4*)(q_ + i * 16));
    const float* qe = qr + ((size_t)b * H_ + wh * 16 + l15) * DR + kd;
    #pragma unroll
    for (int i = 0; i < 4; ++i) Qn[32 + i] = cvt4(*(const f32x4*)(qe + i * 16));
  }

  // staging roles: nope -- lane stages key w*8+(l>>3), 16B-group l&7
  const int skey = w * 8 + (l >> 3);
  const int scol = l & 7;
  f32x4 gk[16], gr[2];

  auto ISSUE = [&](int t) {
    const int kb = kbase + t * TK;
    const size_t br = (size_t)btab[b * 32 + (kb >> 7)] * BS + (kb & (BS - 1));
    const float* kn_ = kvn + (br + skey) * DN + scol * 4;
    #pragma unroll
    for (int j = 0; j < 16; ++j) gk[j] = *(const f32x4*)(kn_ + j * 32);
    #pragma unroll
    for (int s = 0; s < 2; ++s) {
      const int rI = tid * 2 + s;              // rope: key rI>>4, f32x4 rI&15
      gr[s] = *(const f32x4*)(kvr + (br + (rI >> 4)) * DR + (rI & 15) * 4);
    }
    __builtin_amdgcn_sched_barrier(0);
  };
  auto WRITEK = [&](int bf) {
    #pragma unroll
    for (int j = 0; j < 16; ++j) {
      const int slot = (scol + j * 8) ^ (skey & 7);      // 8B slots
      *(f16x4*)(&KT[bf][skey][0] + slot * 4) = cvt4(gk[j]);
    }
    #pragma unroll
    for (int s = 0; s < 2; ++s) {
      const int rI = tid * 2 + s;
      const int key = rI >> 4, col4 = rI & 15;
      const int slot = (128 + col4) ^ (key & 7);
      *(f16x4*)(&KT[bf][key][0] + slot * 4) = cvt4(gr[s]);
    }
  };

  // ---- prologue ----
  ISSUE(0);
  WRITEK(0);                 // compiler inserts the vmcnt wait here
  if (nsb > 1) ISSUE(1);
  ldsbar();

  for (int t = 0; t < nsb; ++t) {
    const int cur = t & 1, nxt = cur ^ 1;

    // ---- QK^T: S^T tile = K.Q^T over 576 dims (dual acc chains) ----
    const int rowA = wk * 16 + l15;
    const _Float16* kA = &KT[cur][rowA][0];
    const int x7 = rowA & 7;
    f32x4 sA = {0.f,0.f,0.f,0.f}, sB = {0.f,0.f,0.f,0.f};
    #pragma unroll
    for (int m = 0; m < 36; m += 2) {
      f16x4 a0 = *(const f16x4*)(kA + (((m * 4 + lg) ^ x7) * 4));
      f16x4 a1 = *(const f16x4*)(kA + ((((m + 1) * 4 + lg) ^ x7) * 4));
      sA = MFMA16(a0, Qn[m],     sA, 0, 0, 0);
      sB = MFMA16(a1, Qn[m + 1], sB, 0, 0, 0);
    }

    // D: row(key-in-half) = kd+r, col(head) = wh*16+l15. Scale+mask+max.
    const int kb = kbase + t * TK;
    float v0[4]; float mx = NEG_INF;
    #pragma unroll
    for (int r = 0; r < 4; ++r) {
      const bool ok = (kb + wk * 16 + kd + r) < klen;
      v0[r] = ok ? (sA[r] + sB[r]) * SCALE_ : NEG_INF;
      mx = fmaxf(mx, v0[r]);
    }
    mx = fmaxf(mx, __shfl_xor(mx, 16));
    mx = fmaxf(mx, __shfl_xor(mx, 32));
    if (lg == 0) m_tab[wk][wh * 16 + l15] = mx;
    ldsbar();                                   // bar1

    // ---- softmax: redundant per-lane max-combine (no extra barrier) ----
    const int hC = wh * 16 + l15;
    const float moC = Mrun[cur][hC];
    const float mnC = fmaxf(fmaxf(m_tab[0][hC], m_tab[1][hC]), moC);
    float p0[4], ls = 0.f;
    #pragma unroll
    for (int r = 0; r < 4; ++r) { p0[r] = exp2f((v0[r] - mnC) * LOG2E); ls += p0[r]; }
    ls += __shfl_xor(ls, 16); ls += __shfl_xor(ls, 32);
    if (lg == 0) l_tab[wk][hC] = ls;
    f16x4 pk;
    #pragma unroll
    for (int r = 0; r < 4; ++r) pk[r] = (_Float16)p0[r];
    *(f16x4*)&Plds[hC][wk * 16 + kd] = pk;
    // rescale acc: fact recomputed per PV-head redundantly
    #pragma unroll
    for (int r = 0; r < 4; ++r) {
      const int h = hw * 16 + kd + r;
      const float mo = Mrun[cur][h];
      const float mn = fmaxf(fmaxf(m_tab[0][h], m_tab[1][h]), mo);
      const float f = exp2f((mo - mn) * LOG2E);
      #pragma unroll
      for (int dt = 0; dt < 16; ++dt) acc[dt][r] *= f;
    }
    if (tid < H_) {                            // Mrun ping-pong update
      const float mo = Mrun[cur][tid];
      Mrun[nxt][tid] = fmaxf(fmaxf(m_tab[0][tid], m_tab[1][tid]), mo);
    }
    ldsbar();                                   // bar2: P/Mrun[nxt] visible

    // ---- staging: consume tile t+1 loads, issue tile t+2 ----
    if (t + 1 < nsb) WRITEK(nxt);               // vmcnt wait lands here
    if (t + 2 < nsb) ISSUE(t + 2);

    if (tid < H_) {                            // Lrun ping-pong update
      const float mo = Mrun[cur][tid], mn = Mrun[nxt][tid];
      const float f = exp2f((mo - mn) * LOG2E);
      Lrun[nxt][tid] = Lrun[cur][tid] * f + l_tab[0][tid] + l_tab[1][tid];
    }

    // ---- PV: wave (hw, dv) -> O[16 heads][256 dims], V from K-LDS ----
    {
      f16x4 pa0 = *(const f16x4*)&Plds[hw * 16 + l15][kd];
      f16x4 pa1 = *(const f16x4*)&Plds[hw * 16 + l15][16 + kd];
      const _Float16* vB = &KT[cur][0][0];
      #pragma unroll
      for (int dt = 0; dt < 16; ++dt) {
        const int cc = dv * 256 + dt * 16 + l15;
        const int sl = cc >> 2, sub = cc & 3;
        f16x4 b0, b1;
        #pragma unroll
        for (int i = 0; i < 4; ++i) {
          const int k0 = kd + i, k1 = 16 + kd + i;
          b0[i] = vB[(size_t)k0 * ROWF + ((sl ^ (k0 & 7)) * 4 + sub)];
          b1[i] = vB[(size_t)k1 * ROWF + ((sl ^ (k1 & 7)) * 4 + sub)];
        }
        acc[dt] = MFMA16(pa0, b0, acc[dt], 0, 0, 0);
        acc[dt] = MFMA16(pa1, b1, acc[dt], 0, 0, 0);
      }
    }
    ldsbar();                                   // bar3: buf reads done
  }

  // ---- write partials: O (unnormalized, f16), m, l ----
  _Float16* pop = po + (size_t)(b * nc + c) * H_ * DN;
  #pragma unroll
  for (int dt = 0; dt < 16; ++dt)
    #pragma unroll
    for (int r = 0; r < 4; ++r)
      pop[(size_t)(hw * 16 + kd + r) * DN + dv * 256 + dt * 16 + l15] =
          (_Float16)acc[dt][r];
  const int fs = nsb & 1;
  if (tid < H_) {
    const size_t o = ((size_t)(b * nc + c) * H_ + tid) * 2;
    ml[o] = Mrun[fs][tid]; ml[o + 1] = Lrun[fs][tid];
  }
}

// Kernel 2: merge chunk partials per (b,h).
__global__ __launch_bounds__(256) void mla_reduce(
    const _Float16* __restrict__ po, const float* __restrict__ ml,
    const int* __restrict__ kseq, float* __restrict__ out,
    const int nc, const int chunk)
{
  const int bh = blockIdx.x;
  const int b = bh >> 5, h = bh & 31;
  const int klen = kseq[b];
  const int na = min(nc, (klen + chunk - 1) / chunk);
  const int tid = threadIdx.x;

  float M = NEG_INF;
  for (int c = 0; c < na; ++c)
    M = fmaxf(M, ml[((size_t)(b * nc + c) * H_ + h) * 2]);

  float s0 = 0.f, s1 = 0.f, den = 0.f;
  for (int c = 0; c < na; ++c) {
    const size_t o = ((size_t)(b * nc + c) * H_ + h) * 2;
    const float e = exp2f((ml[o] - M) * LOG2E);
    den += ml[o + 1] * e;
    const _Float16* p = po + ((size_t)(b * nc + c) * H_ + h) * DN;
    s0 += (float)p[tid] * e;
    s1 += (float)p[tid + 256] * e;
  }
  const float inv = 1.f / den;
  float* op = out + ((size_t)b * H_ + h) * DN;
  op[tid]       = s0 * inv;
  op[tid + 256] = s1 * inv;
}

extern "C" void kernel_launch(void* const* d_in, const int* in_sizes, int n_in,
                              void* d_out, int out_size, void* d_ws, size_t ws_size,
                              hipStream_t stream) {
  const float* qn  = (const float*)d_in[0];
  const float* qr  = (const float*)d_in[1];
  const float* kvn = (const float*)d_in[2];
  const float* kvr = (const float*)d_in[3];
  const int*  btab = (const int*)d_in[4];
  const int*  kseq = (const int*)d_in[6];
  float* out = (float*)d_out;

  // workspace-adaptive chunk count: nc chunks of 4096/nc keys
  int nc = 16;
  while (nc > 1 &&
         ((size_t)B_ * nc * H_ * DN * sizeof(_Float16) +
          (size_t)B_ * nc * H_ * 2 * sizeof(float)) > ws_size)
    nc >>= 1;
  const int chunk = MAXKV / nc;

  _Float16* po = (_Float16*)d_ws;                          // [B][nc][H][DN] f16
  float* ml = (float*)(po + (size_t)B_ * nc * H_ * DN);    // [B][nc][H][2]  f32

  mla_chunk<<<B_ * nc, 256, 0, stream>>>(qn, qr, kvn, kvr, btab, kseq,
                                         po, ml, nc, chunk);
  mla_reduce<<<B_ * H_, 256, 0, stream>>>(po, ml, kseq, out, nc, chunk);
}

// Round 9
// 212.390 us; speedup vs baseline: 1.8305x; 1.8305x over previous
//
#include <hip/hip_runtime.h>

#define B_ 64
#define H_ 32
#define DN 512
#define DR 64
#define BS 128
#define TK 32
#define MAXKV 4096
#define LOG2E 1.44269504088896340736f
#define SCALE_ (1.0f/24.0f)   // 1/sqrt(576)
#define NEG_INF -1e30f

typedef float    f32x4 __attribute__((ext_vector_type(4)));
typedef _Float16 f16x4 __attribute__((ext_vector_type(4)));
typedef _Float16 f16x2 __attribute__((ext_vector_type(2)));

#define MFMA16 __builtin_amdgcn_mfma_f32_16x16x16f16

__device__ __forceinline__ f16x4 cvt4(f32x4 a) {
  f16x2 lo = __builtin_bit_cast(f16x2, __builtin_amdgcn_cvt_pkrtz(a[0], a[1]));
  f16x2 hi = __builtin_bit_cast(f16x2, __builtin_amdgcn_cvt_pkrtz(a[2], a[3]));
  f16x4 r; r[0] = lo[0]; r[1] = lo[1]; r[2] = hi[0]; r[3] = hi[1];
  return r;
}

__device__ __forceinline__ void gl_lds16(const float* g, void* l) {
  __builtin_amdgcn_global_load_lds(
      (const __attribute__((address_space(1))) void*)g,
      (__attribute__((address_space(3))) void*)l, 16, 0, 0);
}

// Stage one 32-key tile (nope [32][512] f32 + rope [32][64] f32) into LDS
// via global_load_lds (no VGPR cost, deep DMA queue). LDS dest is linear
// (base + lane*16); the XOR swizzle (16B slot ^= key&7) is applied on the
// per-lane GLOBAL source; reads use the same XOR (involution).
// 18 instructions per wave.
__device__ __forceinline__ void stage_tile(
    float* kb_lds, float* kr_lds,
    const float* kvn, const float* kvr,
    const size_t blkrow,  // blk*BS + row offset of key 0 of this tile
    const int w, const int lane)
{
  #pragma unroll
  for (int j = 0; j < 16; ++j) {
    const int I  = w * 16 + j;                // 0..63 half-rows
    const int kl = I >> 1;                    // key-local 0..31
    const int sp = ((I & 1) << 6) + lane;     // physical 16B slot 0..127
    const int s  = sp ^ (kl & 7);             // content slot
    gl_lds16(kvn + (blkrow + kl) * DN + s * 4, (char*)kb_lds + I * 1024);
  }
  #pragma unroll
  for (int j = 0; j < 2; ++j) {
    const int I  = w * 2 + j;                 // 0..7 quad-rows
    const int kl = I * 4 + (lane >> 4);       // key-local 0..31
    const int sp = lane & 15;                 // physical slot 0..15
    const int s  = sp ^ (kl & 7);
    gl_lds16(kvr + (blkrow + kl) * DR + s * 4, (char*)kr_lds + I * 1024);
  }
}

// Kernel 1: per (b, chunk-of-128-keys) flash-decode partial. TK=32 tiles,
// 4 waves, SINGLE-buffered f32 K tile in LDS (77,312 B -> 2 blocks/CU).
// Cross-block overlap hides the DMA drain (block B computes while block A
// stages). Q held in f16 registers. 4 barriers/tile.
__global__ __launch_bounds__(256, 1) void mla_chunk(
    const float* __restrict__ qn, const float* __restrict__ qr,
    const float* __restrict__ kvn, const float* __restrict__ kvr,
    const int* __restrict__ btab, const int* __restrict__ kseq,
    _Float16* __restrict__ po, float* __restrict__ ml,
    const int nc, const int chunk)
{
  const int bc = blockIdx.x;
  const int b = bc / nc, c = bc - b * nc;
  const int klen = kseq[b];
  const int kbase = c * chunk;
  if (kbase >= klen) return;
  const int nvalid = min(chunk, klen - kbase);
  const int nsb = (nvalid + TK - 1) / TK;

  const int tid = threadIdx.x;
  const int w = tid >> 6, l = tid & 63, l15 = l & 15, lg = l >> 4;
  const int kd = lg * 4;
  const int wk = w >> 1, wh = w & 1;     // QK roles: key-half, head-half
  const int hw = w >> 1, dv = w & 1;     // PV roles: head-half, dim-half

  __shared__ float KT[TK][DN];           // 65,536 B, swizzled 16B slots
  __shared__ float KR[TK][DR];           //  8,192 B, swizzled
  __shared__ _Float16 Plds[H_][40];      //  2,560 B
  __shared__ float m_tab[2][H_], l_tab[2][H_];
  __shared__ float Mrun[2][H_], Lrun[2][H_];

  if (tid < H_) { Mrun[0][tid] = NEG_INF; Lrun[0][tid] = 0.f; }

  f32x4 acc[16];
  #pragma unroll
  for (int i = 0; i < 16; ++i) acc[i] = (f32x4){0.f, 0.f, 0.f, 0.f};

  // ---- Q fragments (nope 0..31 + rope 32..35) in f16 regs ----
  // B-frag: col = l15 -> head wh*16+l15, k = kd+i.
  f16x4 Qn[36];
  {
    const float* q_ = qn + ((size_t)b * H_ + wh * 16 + l15) * DN + kd;
    #pragma unroll
    for (int i = 0; i < 32; ++i) Qn[i] = cvt4(*(const f32x4*)(q_ + i * 16));
    const float* qe = qr + ((size_t)b * H_ + wh * 16 + l15) * DR + kd;
    #pragma unroll
    for (int i = 0; i < 4; ++i) Qn[32 + i] = cvt4(*(const f32x4*)(qe + i * 16));
  }

  // ---- prologue: stage tile 0 ----
  {
    const size_t br0 = (size_t)btab[b * 32 + (kbase >> 7)] * BS + (kbase & (BS - 1));
    stage_tile(&KT[0][0], &KR[0][0], kvn, kvr, br0, w, l);
  }

  for (int t = 0; t < nsb; ++t) {
    const int cur = t & 1, nxt = cur ^ 1;
    __syncthreads();          // drains DMA (vmcnt 0): tile t ready

    // ---- QK^T: S^T tile = K.Q^T over 576 dims (dual acc chains) ----
    const int rowA = wk * 16 + l15;
    const char* kA = (const char*)&KT[0][0] + rowA * 2048;
    const char* rA = (const char*)&KR[0][0] + rowA * 256;
    const int x7 = rowA & 7;
    f32x4 sA = {0.f,0.f,0.f,0.f}, sB = {0.f,0.f,0.f,0.f};
    #pragma unroll
    for (int m = 0; m < 32; m += 2) {
      f32x4 k0 = *(const f32x4*)(kA + (((m * 4 + lg) ^ x7) << 4));
      f32x4 k1 = *(const f32x4*)(kA + ((((m + 1) * 4 + lg) ^ x7) << 4));
      sA = MFMA16(cvt4(k0), Qn[m],     sA, 0, 0, 0);
      sB = MFMA16(cvt4(k1), Qn[m + 1], sB, 0, 0, 0);
    }
    #pragma unroll
    for (int m = 32; m < 36; m += 2) {
      f32x4 k0 = *(const f32x4*)(rA + ((((m - 32) * 4 + lg) ^ x7) << 4));
      f32x4 k1 = *(const f32x4*)(rA + ((((m - 31) * 4 + lg) ^ x7) << 4));
      sA = MFMA16(cvt4(k0), Qn[m],     sA, 0, 0, 0);
      sB = MFMA16(cvt4(k1), Qn[m + 1], sB, 0, 0, 0);
    }

    // D: row(key) = wk*16 + kd + r, col(head) = wh*16 + l15. Scale+mask+max.
    const int kb = kbase + t * TK;
    float v0[4]; float mx = NEG_INF;
    #pragma unroll
    for (int r = 0; r < 4; ++r) {
      const bool ok = (kb + wk * 16 + kd + r) < klen;
      v0[r] = ok ? (sA[r] + sB[r]) * SCALE_ : NEG_INF;
      mx = fmaxf(mx, v0[r]);
    }
    mx = fmaxf(mx, __shfl_xor(mx, 16));
    mx = fmaxf(mx, __shfl_xor(mx, 32));
    if (lg == 0) m_tab[wk][wh * 16 + l15] = mx;
    __syncthreads();                            // bar1

    // ---- softmax: redundant per-lane max-combine (no extra barrier) ----
    const int hC = wh * 16 + l15;
    const float moC = Mrun[cur][hC];
    const float mnC = fmaxf(fmaxf(m_tab[0][hC], m_tab[1][hC]), moC);
    float p0[4], ls = 0.f;
    #pragma unroll
    for (int r = 0; r < 4; ++r) { p0[r] = exp2f((v0[r] - mnC) * LOG2E); ls += p0[r]; }
    ls += __shfl_xor(ls, 16); ls += __shfl_xor(ls, 32);
    if (lg == 0) l_tab[wk][hC] = ls;
    f16x4 pk;
    #pragma unroll
    for (int r = 0; r < 4; ++r) pk[r] = (_Float16)p0[r];
    *(f16x4*)&Plds[hC][wk * 16 + kd] = pk;
    // rescale acc: fact recomputed per PV-head redundantly
    #pragma unroll
    for (int r = 0; r < 4; ++r) {
      const int h = hw * 16 + kd + r;
      const float mo = Mrun[cur][h];
      const float mn = fmaxf(fmaxf(m_tab[0][h], m_tab[1][h]), mo);
      const float f = exp2f((mo - mn) * LOG2E);
      #pragma unroll
      for (int dt = 0; dt < 16; ++dt) acc[dt][r] *= f;
    }
    if (tid < H_) {                            // Mrun ping-pong update
      const float mo = Mrun[cur][tid];
      Mrun[nxt][tid] = fmaxf(fmaxf(m_tab[0][tid], m_tab[1][tid]), mo);
    }
    __syncthreads();                            // bar2: P/l_tab/Mrun visible

    if (tid < H_) {                            // Lrun ping-pong update
      const float mo = Mrun[cur][tid], mn = Mrun[nxt][tid];
      const float f = exp2f((mo - mn) * LOG2E);
      Lrun[nxt][tid] = Lrun[cur][tid] * f + l_tab[0][tid] + l_tab[1][tid];
    }

    // ---- PV: wave (hw, dv) -> O[16 heads][256 dims], V from K-LDS ----
    {
      f16x4 pa0 = *(const f16x4*)&Plds[hw * 16 + l15][kd];
      f16x4 pa1 = *(const f16x4*)&Plds[hw * 16 + l15][16 + kd];
      const char* vB = (const char*)&KT[0][0];
      #pragma unroll
      for (int dt = 0; dt < 16; ++dt) {
        const int cc = dv * 256 + dt * 16 + l15;
        const int sl = cc >> 2, sub = (cc & 3) << 2;
        float b0f[4], b1f[4];
        #pragma unroll
        for (int i = 0; i < 4; ++i) {
          const int k0 = kd + i, k1 = 16 + kd + i;
          b0f[i] = *(const float*)(vB + k0 * 2048 + (((sl ^ (k0 & 7)) << 4) + sub));
          b1f[i] = *(const float*)(vB + k1 * 2048 + (((sl ^ (k1 & 7)) << 4) + sub));
        }
        f16x4 b0, b1;
        #pragma unroll
        for (int i = 0; i < 4; ++i) {
          b0[i] = (_Float16)b0f[i]; b1[i] = (_Float16)b1f[i];
        }
        acc[dt] = MFMA16(pa0, b0, acc[dt], 0, 0, 0);
        acc[dt] = MFMA16(pa1, b1, acc[dt], 0, 0, 0);
      }
    }
    __syncthreads();                            // bar3: KT reads done

    // ---- stage tile t+1 (drained at next top-of-loop sync) ----
    if (t + 1 < nsb) {
      const int kb2 = kbase + (t + 1) * TK;
      const size_t br2 = (size_t)btab[b * 32 + (kb2 >> 7)] * BS + (kb2 & (BS - 1));
      stage_tile(&KT[0][0], &KR[0][0], kvn, kvr, br2, w, l);
    }
  }

  // ---- write partials: O (unnormalized, f16), m, l ----
  _Float16* pop = po + (size_t)(b * nc + c) * H_ * DN;
  #pragma unroll
  for (int dt = 0; dt < 16; ++dt)
    #pragma unroll
    for (int r = 0; r < 4; ++r)
      pop[(size_t)(hw * 16 + kd + r) * DN + dv * 256 + dt * 16 + l15] =
          (_Float16)acc[dt][r];
  const int fs = nsb & 1;
  if (tid < H_) {
    const size_t o = ((size_t)(b * nc + c) * H_ + tid) * 2;
    ml[o] = Mrun[fs][tid]; ml[o + 1] = Lrun[fs][tid];
  }
}

// Kernel 2: merge chunk partials per (b,h).
__global__ __launch_bounds__(256) void mla_reduce(
    const _Float16* __restrict__ po, const float* __restrict__ ml,
    const int* __restrict__ kseq, float* __restrict__ out,
    const int nc, const int chunk)
{
  const int bh = blockIdx.x;
  const int b = bh >> 5, h = bh & 31;
  const int klen = kseq[b];
  const int na = min(nc, (klen + chunk - 1) / chunk);
  const int tid = threadIdx.x;

  float M = NEG_INF;
  for (int c = 0; c < na; ++c)
    M = fmaxf(M, ml[((size_t)(b * nc + c) * H_ + h) * 2]);

  float s0 = 0.f, s1 = 0.f, den = 0.f;
  for (int c = 0; c < na; ++c) {
    const size_t o = ((size_t)(b * nc + c) * H_ + h) * 2;
    const float e = exp2f((ml[o] - M) * LOG2E);
    den += ml[o + 1] * e;
    const _Float16* p = po + ((size_t)(b * nc + c) * H_ + h) * DN;
    s0 += (float)p[tid] * e;
    s1 += (float)p[tid + 256] * e;
  }
  const float inv = 1.f / den;
  float* op = out + ((size_t)b * H_ + h) * DN;
  op[tid]       = s0 * inv;
  op[tid + 256] = s1 * inv;
}

extern "C" void kernel_launch(void* const* d_in, const int* in_sizes, int n_in,
                              void* d_out, int out_size, void* d_ws, size_t ws_size,
                              hipStream_t stream) {
  const float* qn  = (const float*)d_in[0];
  const float* qr  = (const float*)d_in[1];
  const float* kvn = (const float*)d_in[2];
  const float* kvr = (const float*)d_in[3];
  const int*  btab = (const int*)d_in[4];
  const int*  kseq = (const int*)d_in[6];
  float* out = (float*)d_out;

  // workspace-adaptive chunk count: nc chunks of 4096/nc keys
  int nc = 32;
  while (nc > 1 &&
         ((size_t)B_ * nc * H_ * DN * sizeof(_Float16) +
          (size_t)B_ * nc * H_ * 2 * sizeof(float)) > ws_size)
    nc >>= 1;
  const int chunk = MAXKV / nc;

  _Float16* po = (_Float16*)d_ws;                          // [B][nc][H][DN] f16
  float* ml = (float*)(po + (size_t)B_ * nc * H_ * DN);    // [B][nc][H][2]  f32

  mla_chunk<<<B_ * nc, 256, 0, stream>>>(qn, qr, kvn, kvr, btab, kseq,
                                         po, ml, nc, chunk);
  mla_reduce<<<B_ * H_, 256, 0, stream>>>(po, ml, kseq, out, nc, chunk);
}